// Round 3
// baseline (241.599 us; speedup 1.0000x reference)
//
#include <hip/hip_runtime.h>

// IF neuron, multi-step, hard reset:
//   h_t = x_t + v_{t-1};  s_t = (h_t >= 1.0);  v_t = s_t ? 0 : h_t
//
// R9 theory: all ILP-side structures (width f2/f4, C=1..4 columns,
// prefetch D=0..4, phase split, NT/plain stores) land in a ±10% band
// at 2.5-2.75 TB/s -> structure-invariant. The one untested axis is
// TLP: all prior variants ran 4-16 waves/CU. The m13 copy ubench
// (6.29 TB/s, same per-thread load+store shape) runs max-occupancy.
// At 24 VGPR we can hold 32 waves/CU. Mechanism: keeping memory queues
// full through ~900cy latency bubbles and drain skew needs issue-
// eligible waves, not deeper per-wave FIFOs (deeper prefetch measured
// neutral-to-negative).
//
// So: simplest f2 kernel, one column/thread, no manual prefetch,
// plain stores, 524288 threads = 2048 blocks = 8 blocks/CU = 100% occ.
// Full unroll over T lets the compiler pipeline 1-2 loads ahead.

typedef float v2f __attribute__((ext_vector_type(2)));

template <int T>
__global__ __launch_bounds__(256) void if_node_f2_tlp(
    const float* __restrict__ x,    // (T, N)
    const float* __restrict__ v0,   // (N,)
    float* __restrict__ out,        // (T, N)
    long n2)                        // N/2
{
    long i = (long)blockIdx.x * blockDim.x + threadIdx.x;
    if (i >= n2) return;

    const v2f* __restrict__ x2 = (const v2f*)x;
    v2f*       __restrict__ o2 = (v2f*)out;

    v2f v = ((const v2f*)v0)[i];

#pragma unroll
    for (int t = 0; t < T; ++t) {
        v2f xv = x2[(long)t * n2 + i];
        float hx = xv.x + v.x;
        float hy = xv.y + v.y;
        bool sx = hx >= 1.0f;       // == (h - 1.0f) >= 0 for all finite h
        bool sy = hy >= 1.0f;
        v2f s;
        s.x = sx ? 1.0f : 0.0f;
        s.y = sy ? 1.0f : 0.0f;
        v.x = sx ? 0.0f : hx;
        v.y = sy ? 0.0f : hy;
        o2[(long)t * n2 + i] = s;
    }
}

// Fallbacks for shapes the fast path doesn't cover.
__global__ __launch_bounds__(256) void if_node_f2_generic(
    const float* __restrict__ x, const float* __restrict__ v0,
    float* __restrict__ out, long n2, int T)
{
    long i = (long)blockIdx.x * blockDim.x + threadIdx.x;
    if (i >= n2) return;
    const v2f* x2 = (const v2f*)x;
    v2f*       o2 = (v2f*)out;
    v2f v = ((const v2f*)v0)[i];
    for (int t = 0; t < T; ++t) {
        v2f xv = x2[(long)t * n2 + i];
        float hx = xv.x + v.x;
        float hy = xv.y + v.y;
        bool sx = hx >= 1.0f;
        bool sy = hy >= 1.0f;
        v2f s;
        s.x = sx ? 1.0f : 0.0f;
        s.y = sy ? 1.0f : 0.0f;
        v.x = sx ? 0.0f : hx;
        v.y = sy ? 0.0f : hy;
        o2[(long)t * n2 + i] = s;
    }
}

__global__ __launch_bounds__(256) void if_node_scalar(
    const float* __restrict__ x, const float* __restrict__ v0,
    float* __restrict__ out, long n, int T)
{
    long i = (long)blockIdx.x * blockDim.x + threadIdx.x;
    if (i >= n) return;
    float v = v0[i];
    for (int t = 0; t < T; ++t) {
        float h = x[(long)t * n + i] + v;
        bool s = h >= 1.0f;
        out[(long)t * n + i] = s ? 1.0f : 0.0f;
        v = s ? 0.0f : h;
    }
}

extern "C" void kernel_launch(void* const* d_in, const int* in_sizes, int n_in,
                              void* d_out, int out_size, void* d_ws, size_t ws_size,
                              hipStream_t stream) {
    const float* x  = (const float*)d_in[0];   // (T, B, D) fp32
    const float* v0 = (const float*)d_in[1];   // (B, D) fp32
    float* out = (float*)d_out;                // (T, B, D) fp32

    long n = in_sizes[1];                      // B*D
    int  T = (int)(in_sizes[0] / n);           // 32

    int block = 256;
    if (T == 32 && (n & 1) == 0) {
        long n2 = n >> 1;                      // float2 elements
        long grid = (n2 + block - 1) / block;  // 2048 blocks at N=1M
        if_node_f2_tlp<32><<<dim3((unsigned)grid), dim3(block), 0, stream>>>(
            x, v0, out, n2);
    } else if ((n & 1) == 0) {
        long n2 = n >> 1;
        long grid = (n2 + block - 1) / block;
        if_node_f2_generic<<<dim3((unsigned)grid), dim3(block), 0, stream>>>(
            x, v0, out, n2, T);
    } else {
        long grid = (n + block - 1) / block;
        if_node_scalar<<<dim3((unsigned)grid), dim3(block), 0, stream>>>(
            x, v0, out, n, T);
    }
}

// Round 4
// 221.706 us; speedup vs baseline: 1.0897x; 1.0897x over previous
//
#include <hip/hip_runtime.h>

// IF neuron, multi-step, hard reset:
//   h_t = x_t + v_{t-1};  s_t = (h_t >= 1.0);  v_t = s_t ? 0 : h_t
//
// R10 theory: every CU-side structure (width, columns, prefetch depth,
// phase split, store cache policy, waves/CU 8..32) lands at 74-89 us /
// ~2.5 TB/s -> the memory system's service rate for this pattern is the
// limit, not the CU. Remaining mechanism: L3 allocation contention.
// Read stream (128 MiB x) + write-allocate stream (128 MiB out) = exactly
// the 256 MiB L3, continuously evicting each other (FETCH shows only half
// of x hitting). The 6.3 TB/s copy ubench doesn't thrash L3 this way.
// R8 kept writes out of L3 (no change); reads were never kept out.
// This round: R4 structure (f2 x C=4, no t-prefetch, NT stores - the
// 74 us best) + __builtin_nontemporal_load on x. Single variable vs R4.
//
// Fingerprint: FETCH_SIZE 67.6 MB -> ~131 MB. If time doesn't improve,
// L3 contention is excluded and ~2.5 TB/s is pattern-intrinsic.

typedef float v2f __attribute__((ext_vector_type(2)));

template <int T, int C>
__global__ __launch_bounds__(256) void if_node_mc_ntl(
    const float* __restrict__ x,    // (T, N)
    const float* __restrict__ v0,   // (N,)
    float* __restrict__ out,        // (T, N)
    long q)                         // column stride in float2 elems = (N/2)/C
{
    long i = (long)blockIdx.x * blockDim.x + threadIdx.x;
    if (i >= q) return;

    const v2f* __restrict__ x2 = (const v2f*)x;
    v2f*       __restrict__ o2 = (v2f*)out;
    const v2f* __restrict__ vv = (const v2f*)v0;

    const long n2 = q * C;

    v2f v[C];
#pragma unroll
    for (int c = 0; c < C; ++c)
        v[c] = vv[i + (long)c * q];

#pragma unroll
    for (int t = 0; t < T; ++t) {
        v2f xv[C];
#pragma unroll
        for (int c = 0; c < C; ++c)
            xv[c] = __builtin_nontemporal_load(&x2[(long)t * n2 + i + (long)c * q]);

#pragma unroll
        for (int c = 0; c < C; ++c) {
            float hx = xv[c].x + v[c].x;
            float hy = xv[c].y + v[c].y;
            bool sx = hx >= 1.0f;   // == (h - 1.0f) >= 0 for all finite h
            bool sy = hy >= 1.0f;
            v2f s;
            s.x = sx ? 1.0f : 0.0f;
            s.y = sy ? 1.0f : 0.0f;
            v[c].x = sx ? 0.0f : hx;
            v[c].y = sy ? 0.0f : hy;
            __builtin_nontemporal_store(s, &o2[(long)t * n2 + i + (long)c * q]);
        }
    }
}

// Fallbacks for shapes the fast path doesn't cover.
__global__ __launch_bounds__(256) void if_node_f2_generic(
    const float* __restrict__ x, const float* __restrict__ v0,
    float* __restrict__ out, long n2, int T)
{
    long i = (long)blockIdx.x * blockDim.x + threadIdx.x;
    if (i >= n2) return;
    const v2f* x2 = (const v2f*)x;
    v2f*       o2 = (v2f*)out;
    v2f v = ((const v2f*)v0)[i];
    for (int t = 0; t < T; ++t) {
        v2f xv = x2[(long)t * n2 + i];
        float hx = xv.x + v.x;
        float hy = xv.y + v.y;
        bool sx = hx >= 1.0f;
        bool sy = hy >= 1.0f;
        v2f s;
        s.x = sx ? 1.0f : 0.0f;
        s.y = sy ? 1.0f : 0.0f;
        v.x = sx ? 0.0f : hx;
        v.y = sy ? 0.0f : hy;
        o2[(long)t * n2 + i] = s;
    }
}

__global__ __launch_bounds__(256) void if_node_scalar(
    const float* __restrict__ x, const float* __restrict__ v0,
    float* __restrict__ out, long n, int T)
{
    long i = (long)blockIdx.x * blockDim.x + threadIdx.x;
    if (i >= n) return;
    float v = v0[i];
    for (int t = 0; t < T; ++t) {
        float h = x[(long)t * n + i] + v;
        bool s = h >= 1.0f;
        out[(long)t * n + i] = s ? 1.0f : 0.0f;
        v = s ? 0.0f : h;
    }
}

extern "C" void kernel_launch(void* const* d_in, const int* in_sizes, int n_in,
                              void* d_out, int out_size, void* d_ws, size_t ws_size,
                              hipStream_t stream) {
    const float* x  = (const float*)d_in[0];   // (T, B, D) fp32
    const float* v0 = (const float*)d_in[1];   // (B, D) fp32
    float* out = (float*)d_out;                // (T, B, D) fp32

    long n = in_sizes[1];                      // B*D
    int  T = (int)(in_sizes[0] / n);           // 32

    int block = 256;
    constexpr int C = 4;
    if (T == 32 && (n % (2 * C)) == 0) {
        long n2 = n >> 1;          // float2 elements
        long q  = n2 / C;          // per-column float2 elements
        long grid = (q + block - 1) / block;
        if_node_mc_ntl<32, C><<<dim3((unsigned)grid), dim3(block), 0, stream>>>(
            x, v0, out, q);
    } else if ((n & 1) == 0) {
        long n2 = n >> 1;
        long grid = (n2 + block - 1) / block;
        if_node_f2_generic<<<dim3((unsigned)grid), dim3(block), 0, stream>>>(
            x, v0, out, n2, T);
    } else {
        long grid = (n + block - 1) / block;
        if_node_scalar<<<dim3((unsigned)grid), dim3(block), 0, stream>>>(
            x, v0, out, n, T);
    }
}